// Round 8
// baseline (1046.473 us; speedup 1.0000x reference)
//
#include <hip/hip_runtime.h>

__device__ __forceinline__ float lrelu(float v){ return v > 0.f ? v : 0.01f*v; }

// bf16 helpers (RNE pack; unpack via shift)
__device__ __forceinline__ unsigned short f2bf(float f){
    union{float f; unsigned int i;} v; v.f = f;
    unsigned int u = v.i;
    return (unsigned short)((u + 0x7fffu + ((u >> 16) & 1u)) >> 16);
}
__device__ __forceinline__ unsigned int pack2(float a, float b){
    return (unsigned int)f2bf(a) | ((unsigned int)f2bf(b) << 16);
}
__device__ __forceinline__ float bflo(unsigned int u){
    union{unsigned int i; float f;} v; v.i = u << 16; return v.f;
}
__device__ __forceinline__ float bfhi(unsigned int u){
    union{unsigned int i; float f;} v; v.i = u & 0xffff0000u; return v.f;
}
__device__ __forceinline__ float bf2f(unsigned short s){
    union{unsigned int i; float f;} v; v.i = ((unsigned int)s) << 16; return v.f;
}

// ================= CSR build =================================================
__global__ __launch_bounds__(256) void k_hist(
    const int* __restrict__ ei, int* __restrict__ deg, int E)
{
    int e = blockIdx.x * 256 + threadIdx.x;
    if (e >= E) return;
    atomicAdd(&deg[ei[E + e]], 1);
}

__global__ __launch_bounds__(256) void k_scan1(
    const int* __restrict__ deg, int* __restrict__ rowptr,
    int* __restrict__ bsum, int N)
{
    __shared__ int sh[256];
    int t = threadIdx.x;
    int i = blockIdx.x * 256 + t;
    int v = (i < N) ? deg[i] : 0;
    sh[t] = v;
    __syncthreads();
    #pragma unroll
    for (int off = 1; off < 256; off <<= 1) {
        int add = (t >= off) ? sh[t - off] : 0;
        __syncthreads();
        sh[t] += add;
        __syncthreads();
    }
    if (i < N) rowptr[i] = sh[t] - v;
    if (t == 255) bsum[blockIdx.x] = sh[t];
}

__global__ __launch_bounds__(512) void k_scan2(int* __restrict__ bsum, int nb)
{
    __shared__ int sh[512];
    int t = threadIdx.x;
    int v = (t < nb) ? bsum[t] : 0;
    sh[t] = v;
    __syncthreads();
    #pragma unroll
    for (int off = 1; off < 512; off <<= 1) {
        int add = (t >= off) ? sh[t - off] : 0;
        __syncthreads();
        sh[t] += add;
        __syncthreads();
    }
    if (t < nb) bsum[t] = sh[t] - v;
}

__global__ __launch_bounds__(256) void k_scan3(
    int* __restrict__ rowptr, int* __restrict__ cursor,
    const int* __restrict__ bsum, int N)
{
    int i = blockIdx.x * 256 + threadIdx.x;
    if (i >= N) return;
    int rp = rowptr[i] + bsum[i >> 8];
    rowptr[i] = rp;
    cursor[i] = rp;
}

// cast x -> bf16 (8 floats / thread)
__global__ __launch_bounds__(256) void k_castx(
    const float* __restrict__ x, unsigned int* __restrict__ xb, int M8)
{
    int i = blockIdx.x * 256 + threadIdx.x;      // i indexes groups of 8 floats
    if (i >= M8) return;
    const float4* p = reinterpret_cast<const float4*>(x) + (size_t)i * 2;
    float4 a = p[0], b = p[1];
    uint4 o;
    o.x = pack2(a.x, a.y); o.y = pack2(a.z, a.w);
    o.z = pack2(b.x, b.y); o.w = pack2(b.z, b.w);
    reinterpret_cast<uint4*>(xb)[i] = o;
}

// scatter: csr2[slot]={src,dst}; eab[slot]=16 bf16 of ea row (CSR order!)
__global__ __launch_bounds__(256) void k_scatter(
    const int* __restrict__ ei, const float* __restrict__ ea,
    int* __restrict__ cursor, int2* __restrict__ csr2,
    uint4* __restrict__ eab, int E)
{
    int e = blockIdx.x * 256 + threadIdx.x;
    if (e >= E) return;
    int s = ei[e];
    int d = ei[E + e];
    int slot = atomicAdd(&cursor[d], 1);
    const float4* p = reinterpret_cast<const float4*>(ea) + (size_t)e * 4;
    float4 a = p[0], b = p[1], c = p[2], f = p[3];
    uint4 o0, o1;
    o0.x = pack2(a.x, a.y); o0.y = pack2(a.z, a.w);
    o0.z = pack2(b.x, b.y); o0.w = pack2(b.z, b.w);
    o1.x = pack2(c.x, c.y); o1.y = pack2(c.z, c.w);
    o1.z = pack2(f.x, f.y); o1.w = pack2(f.z, f.w);
    eab[(size_t)slot * 2]     = o0;
    eab[(size_t)slot * 2 + 1] = o1;
    int2 r; r.x = s; r.y = d;
    csr2[slot] = r;
}

// ============ conv1 aggregation: edge-major bf16, SW-pipelined ===============
#define SPW1 128
__global__ __launch_bounds__(256) void k_agg1(
    const unsigned short* __restrict__ xb, const uint4* __restrict__ eab,
    const float* __restrict__ We, const float* __restrict__ be,
    const int2* __restrict__ csr2, float* __restrict__ agg, int E)
{
    const int tid = threadIdx.x;
    const int c = tid & 31;
    const int half = (tid >> 5) & 1;
    const int wave = __builtin_amdgcn_readfirstlane((blockIdx.x * 256 + tid) >> 6);
    const long s0 = (long)wave * SPW1;
    if (s0 >= E) return;
    const long send = (s0 + SPW1 < (long)E) ? s0 + SPW1 : (long)E;

    float w[16];
    #pragma unroll
    for (int k = 0; k < 16; ++k) w[k] = We[k * 32 + c];
    const float bias = be[c];

    long sl = s0 + half;
    if (sl >= send) return;

    int2 rec = csr2[sl];
    float xv = bf2f(xb[(size_t)rec.x * 32 + c]);
    uint4 a0 = eab[sl * 2], a1 = eab[sl * 2 + 1];
    int cur = rec.y;
    float acc = 0.f;
    bool more = true;
    do {
        long nxt = sl + 2;
        more = (nxt < send);
        int2 recn; float xvn; uint4 b0, b1;
        if (more) {                          // prefetch next slot
            recn = csr2[nxt];
            xvn = bf2f(xb[(size_t)recn.x * 32 + c]);
            b0 = eab[nxt * 2]; b1 = eab[nxt * 2 + 1];
        }
        if (rec.y != cur) {
            atomicAdd(&agg[(size_t)cur * 32 + c], acc);
            acc = 0.f; cur = rec.y;
        }
        float m = bias;
        m = fmaf(bflo(a0.x), w[0],  m); m = fmaf(bfhi(a0.x), w[1],  m);
        m = fmaf(bflo(a0.y), w[2],  m); m = fmaf(bfhi(a0.y), w[3],  m);
        m = fmaf(bflo(a0.z), w[4],  m); m = fmaf(bfhi(a0.z), w[5],  m);
        m = fmaf(bflo(a0.w), w[6],  m); m = fmaf(bfhi(a0.w), w[7],  m);
        m = fmaf(bflo(a1.x), w[8],  m); m = fmaf(bfhi(a1.x), w[9],  m);
        m = fmaf(bflo(a1.y), w[10], m); m = fmaf(bfhi(a1.y), w[11], m);
        m = fmaf(bflo(a1.z), w[12], m); m = fmaf(bfhi(a1.z), w[13], m);
        m = fmaf(bflo(a1.w), w[14], m); m = fmaf(bfhi(a1.w), w[15], m);
        m += xv;
        acc += (m > 0.f ? m : 0.f);
        if (more) { rec = recn; xv = xvn; a0 = b0; a1 = b1; }
        sl = nxt;
    } while (more);
    atomicAdd(&agg[(size_t)cur * 32 + c], acc);
}

// ============ conv2 aggregation: edge-major bf16, wave-uniform ===============
#define SPW2 64
__global__ __launch_bounds__(256) void k_agg2(
    const unsigned short* __restrict__ h1b, const uint4* __restrict__ eab,
    const float* __restrict__ We, const float* __restrict__ be,
    const int2* __restrict__ csr2, float* __restrict__ agg, int E)
{
    const int tid = threadIdx.x;
    const int c = tid & 63;
    const int wave = __builtin_amdgcn_readfirstlane((blockIdx.x * 256 + tid) >> 6);
    const long s0 = (long)wave * SPW2;
    if (s0 >= E) return;
    const long send = (s0 + SPW2 < (long)E) ? s0 + SPW2 : (long)E;

    float w[16];
    #pragma unroll
    for (int k = 0; k < 16; ++k) w[k] = We[k * 64 + c];
    const float bias = be[c];

    long sl = s0;
    int2 rec = csr2[sl];                     // wave-uniform -> s_load
    float hv = bf2f(h1b[(size_t)rec.x * 64 + c]);
    uint4 a0 = eab[sl * 2], a1 = eab[sl * 2 + 1];   // uniform stream
    int cur = rec.y;
    bool owned = false;
    float acc = 0.f;
    bool more = true;
    do {
        long nxt = sl + 1;
        more = (nxt < send);
        int2 recn; float hvn; uint4 b0, b1;
        if (more) {                          // prefetch next slot
            recn = csr2[nxt];
            hvn = bf2f(h1b[(size_t)recn.x * 64 + c]);
            b0 = eab[nxt * 2]; b1 = eab[nxt * 2 + 1];
        }
        if (rec.y != cur) {                  // wave-uniform branch
            if (owned) agg[(size_t)cur * 64 + c] = acc;
            else       atomicAdd(&agg[(size_t)cur * 64 + c], acc);
            acc = 0.f; cur = rec.y; owned = true;
        }
        float m = bias;
        m = fmaf(bflo(a0.x), w[0],  m); m = fmaf(bfhi(a0.x), w[1],  m);
        m = fmaf(bflo(a0.y), w[2],  m); m = fmaf(bfhi(a0.y), w[3],  m);
        m = fmaf(bflo(a0.z), w[4],  m); m = fmaf(bfhi(a0.z), w[5],  m);
        m = fmaf(bflo(a0.w), w[6],  m); m = fmaf(bfhi(a0.w), w[7],  m);
        m = fmaf(bflo(a1.x), w[8],  m); m = fmaf(bfhi(a1.x), w[9],  m);
        m = fmaf(bflo(a1.y), w[10], m); m = fmaf(bfhi(a1.y), w[11], m);
        m = fmaf(bflo(a1.z), w[12], m); m = fmaf(bfhi(a1.z), w[13], m);
        m = fmaf(bflo(a1.w), w[14], m); m = fmaf(bfhi(a1.w), w[15], m);
        m += hv;
        acc += (m > 0.f ? m : 0.f);
        if (more) { rec = recn; hv = hvn; a0 = b0; a1 = b1; }
        sl = nxt;
    } while (more);
    atomicAdd(&agg[(size_t)cur * 64 + c], acc);
}

// ============ conv1 node nn, fused; writes h1 fp32 + h1b bf16 ================
__global__ __launch_bounds__(256, 4) void k_mlp1(
    const float* __restrict__ x, const float* __restrict__ agg1,
    const float* __restrict__ W1a, const float* __restrict__ b1a,
    const float* __restrict__ W1b, const float* __restrict__ b1b,
    float* __restrict__ h1, unsigned int* __restrict__ h1b, int N)
{
    __shared__ float ts[64][33];
    const int tid = threadIdx.x;
    const int n0 = blockIdx.x * 64;
    const int row = tid & 63;
    const int grp = __builtin_amdgcn_readfirstlane(tid >> 6);
    const int g = n0 + row;

    float hv[32];
    if (g < N) {
        const float4* xp = reinterpret_cast<const float4*>(x) + (size_t)g * 8;
        const float4* ap = reinterpret_cast<const float4*>(agg1) + (size_t)g * 8;
        #pragma unroll
        for (int q = 0; q < 8; ++q) {
            float4 a = xp[q], b = ap[q];
            hv[4*q+0]=a.x+b.x; hv[4*q+1]=a.y+b.y;
            hv[4*q+2]=a.z+b.z; hv[4*q+3]=a.w+b.w;
        }
    } else {
        #pragma unroll
        for (int q = 0; q < 32; ++q) hv[q] = 0.f;
    }

    {
        const int c0 = grp * 8;
        float acc[8];
        #pragma unroll
        for (int i = 0; i < 8; ++i) acc[i] = b1a[c0 + i];
        for (int k = 0; k < 32; ++k) {
            float h = hv[k];
            const float* w = W1a + k*32 + c0;
            #pragma unroll
            for (int i = 0; i < 8; ++i) acc[i] = fmaf(h, w[i], acc[i]);
        }
        #pragma unroll
        for (int i = 0; i < 8; ++i) ts[row][c0 + i] = lrelu(acc[i]);
    }
    __syncthreads();

    {
        const int c0 = grp * 16;
        float acc[16];
        #pragma unroll
        for (int i = 0; i < 16; ++i) acc[i] = b1b[c0 + i];
        for (int k = 0; k < 32; ++k) {
            float tv = ts[row][k];
            const float* w = W1b + k*64 + c0;
            #pragma unroll
            for (int i = 0; i < 16; ++i) acc[i] = fmaf(tv, w[i], acc[i]);
        }
        if (g < N) {
            #pragma unroll
            for (int i = 0; i < 16; ++i) acc[i] = lrelu(acc[i]);
            float4* op = reinterpret_cast<float4*>(h1) + (size_t)g*16 + (c0>>2);
            #pragma unroll
            for (int q = 0; q < 4; ++q) {
                float4 o;
                o.x = acc[4*q+0]; o.y = acc[4*q+1];
                o.z = acc[4*q+2]; o.w = acc[4*q+3];
                op[q] = o;
            }
            uint4 p0, p1;
            p0.x = pack2(acc[0],  acc[1]);  p0.y = pack2(acc[2],  acc[3]);
            p0.z = pack2(acc[4],  acc[5]);  p0.w = pack2(acc[6],  acc[7]);
            p1.x = pack2(acc[8],  acc[9]);  p1.y = pack2(acc[10], acc[11]);
            p1.z = pack2(acc[12], acc[13]); p1.w = pack2(acc[14], acc[15]);
            uint4* bp = reinterpret_cast<uint4*>(h1b + (size_t)g*32 + (c0>>1));
            bp[0] = p0; bp[1] = p1;
        }
    }
}

// ============ conv2 node nn, fused; h2 stored bf16 ===========================
__global__ __attribute__((amdgpu_flat_work_group_size(256, 256)))
           __attribute__((amdgpu_waves_per_eu(4, 4)))
void k_mlp2(
    const float* __restrict__ h1, const float* __restrict__ agg2,
    const float* __restrict__ W2a, const float* __restrict__ b2a,
    const float* __restrict__ W2b, const float* __restrict__ b2b,
    unsigned int* __restrict__ h2b, int N)
{
    __shared__ float ts[64][129];
    const int tid = threadIdx.x;
    const int n0 = blockIdx.x * 64;
    const int row = tid & 63;
    const int grp = __builtin_amdgcn_readfirstlane(tid >> 6);
    const int g = n0 + row;
    const bool valid = (g < N);

    // phase 1: ts[row][32*grp .. +32] = lrelu(rowvec @ W2a + b2a), chunked hv
    {
        const int c0 = grp * 32;
        float acc[32];
        #pragma unroll
        for (int i = 0; i < 32; ++i) acc[i] = b2a[c0 + i];
        #pragma unroll 1
        for (int kc = 0; kc < 4; ++kc) {
            float hv[16];
            if (valid) {
                const float4* xp = reinterpret_cast<const float4*>(h1)
                                   + (size_t)g * 16 + kc * 4;
                const float4* ap = reinterpret_cast<const float4*>(agg2)
                                   + (size_t)g * 16 + kc * 4;
                #pragma unroll
                for (int q = 0; q < 4; ++q) {
                    float4 a = xp[q], b = ap[q];
                    hv[4*q+0]=a.x+b.x; hv[4*q+1]=a.y+b.y;
                    hv[4*q+2]=a.z+b.z; hv[4*q+3]=a.w+b.w;
                }
            } else {
                #pragma unroll
                for (int q = 0; q < 16; ++q) hv[q] = 0.f;
            }
            #pragma unroll
            for (int k2 = 0; k2 < 16; ++k2) {
                const float* w = W2a + (kc*16 + k2)*128 + c0;
                float h = hv[k2];
                #pragma unroll
                for (int i = 0; i < 32; ++i) acc[i] = fmaf(h, w[i], acc[i]);
            }
        }
        #pragma unroll
        for (int i = 0; i < 32; ++i) ts[row][c0 + i] = lrelu(acc[i]);
    }
    __syncthreads();

    // phase 2: h2b[row][64*grp .. +64], two 32-col chunks, bf16 stores
    #pragma unroll 1
    for (int ch = 0; ch < 2; ++ch) {
        const int c0 = grp * 64 + ch * 32;
        float acc[32];
        #pragma unroll
        for (int i = 0; i < 32; ++i) acc[i] = b2b[c0 + i];
        for (int k = 0; k < 128; ++k) {
            float tv = ts[row][k];
            const float* w = W2b + k*256 + c0;
            #pragma unroll
            for (int i = 0; i < 32; ++i) acc[i] = fmaf(tv, w[i], acc[i]);
        }
        if (valid) {
            uint4* op = reinterpret_cast<uint4*>(h2b + (size_t)g*128 + (c0>>1));
            #pragma unroll
            for (int q = 0; q < 4; ++q) {
                uint4 o;
                o.x = pack2(lrelu(acc[8*q+0]), lrelu(acc[8*q+1]));
                o.y = pack2(lrelu(acc[8*q+2]), lrelu(acc[8*q+3]));
                o.z = pack2(lrelu(acc[8*q+4]), lrelu(acc[8*q+5]));
                o.w = pack2(lrelu(acc[8*q+6]), lrelu(acc[8*q+7]));
                op[q] = o;
            }
        }
    }
}

// ---------------- global_add_pool over sorted batch ids (bf16 h2) -------------
__global__ __launch_bounds__(256) void k_pool(
    const unsigned short* __restrict__ h2b, const int* __restrict__ batch,
    float* __restrict__ g, int N)
{
    int c = threadIdx.x;
    int n0 = blockIdx.x * 128;
    int nend = n0 + 128; if (nend > N) nend = N;
    float acc = 0.f;
    int cur = batch[n0];
    for (int n = n0; n < nend; ++n) {
        int b = batch[n];
        if (b != cur) {
            atomicAdd(&g[(size_t)cur*256 + c], acc);
            acc = 0.f; cur = b;
        }
        acc += bf2f(h2b[(size_t)n*256 + c]);
    }
    atomicAdd(&g[(size_t)cur*256 + c], acc);
}

// ---------------- head MLP -----------------------------------------------------
__global__ __launch_bounds__(256) void k_head(
    const float* __restrict__ g,
    const float* __restrict__ Wf0, const float* __restrict__ bf0,
    const float* __restrict__ Wf1, const float* __restrict__ bf1,
    const float* __restrict__ Wf2, const float* __restrict__ bf2,
    const float* __restrict__ Wr,  const float* __restrict__ br,
    float* __restrict__ out)
{
    __shared__ float buf[256];
    __shared__ float t0[128];
    __shared__ float t1[64];
    __shared__ float t2[32];
    int gid = blockIdx.x, tid = threadIdx.x;
    buf[tid] = g[(size_t)gid*256 + tid];
    __syncthreads();
    if (tid < 128) {
        float acc = bf0[tid];
        for (int k = 0; k < 256; ++k) acc = fmaf(buf[k], Wf0[k*128 + tid], acc);
        t0[tid] = lrelu(acc);
    }
    __syncthreads();
    if (tid < 64) {
        float acc = bf1[tid];
        for (int k = 0; k < 128; ++k) acc = fmaf(t0[k], Wf1[k*64 + tid], acc);
        t1[tid] = lrelu(acc);
    }
    __syncthreads();
    if (tid < 32) {
        float acc = bf2[tid];
        for (int k = 0; k < 64; ++k) acc = fmaf(t1[k], Wf2[k*32 + tid], acc);
        t2[tid] = lrelu(acc);
    }
    __syncthreads();
    if (tid == 0) {
        float acc = br[0];
        for (int k = 0; k < 32; ++k) acc = fmaf(t2[k], Wr[k], acc);
        out[gid] = acc;
    }
}

extern "C" void kernel_launch(void* const* d_in, const int* in_sizes, int n_in,
                              void* d_out, int out_size, void* d_ws, size_t ws_size,
                              hipStream_t stream)
{
    const float* x     = (const float*)d_in[0];
    const int*   ei    = (const int*)d_in[1];
    const float* ea    = (const float*)d_in[2];
    const int*   batch = (const int*)d_in[3];
    const float* We1=(const float*)d_in[4],  *be1=(const float*)d_in[5];
    const float* W1a=(const float*)d_in[6],  *b1a=(const float*)d_in[7];
    const float* W1b=(const float*)d_in[8],  *b1b=(const float*)d_in[9];
    const float* We2=(const float*)d_in[10], *be2=(const float*)d_in[11];
    const float* W2a=(const float*)d_in[12], *b2a=(const float*)d_in[13];
    const float* W2b=(const float*)d_in[14], *b2b=(const float*)d_in[15];
    const float* Wf0=(const float*)d_in[16], *bf0=(const float*)d_in[17];
    const float* Wf1=(const float*)d_in[18], *bf1=(const float*)d_in[19];
    const float* Wf2=(const float*)d_in[20], *bf2=(const float*)d_in[21];
    const float* Wr =(const float*)d_in[22], *br =(const float*)d_in[23];

    const int N = in_sizes[0] / 32;
    const int E = in_sizes[1] / 2;
    const int G = out_size;
    const int nb = (N + 255) / 256;
    const int nb64 = (N + 63) / 64;

    // ---- workspace layout ----
    // zeroed prefix: [deg N][gbuf G*256 f32][agg1 N*32 f32][agg2 N*64 f32]
    char* p = (char*)d_ws;
    int*   deg     = (int*)p;                 p += (size_t)N * 4;
    float* gbuf    = (float*)p;               p += (size_t)G * 256 * 4;
    float* agg1    = (float*)p;               p += (size_t)N * 32 * 4;
    float* agg2    = (float*)p;               p += (size_t)N * 64 * 4;
    size_t zero_bytes = (size_t)(p - (char*)d_ws);
    int*   rowptr  = (int*)p;                 p += (size_t)N * 4;
    int*   cursor  = (int*)p;                 p += (size_t)N * 4;
    int*   bsum    = (int*)p;                 p += 512 * 4;
    p = (char*)(((uintptr_t)p + 15) & ~(uintptr_t)15);
    int2*  csr2    = (int2*)p;                p += (size_t)E * 8;
    uint4* eab     = (uint4*)p;               p += (size_t)E * 32;   // 16 bf16/edge
    unsigned short* xb  = (unsigned short*)p; p += (size_t)N * 32 * 2;
    float* h1      = (float*)p;               p += (size_t)N * 64 * 4;
    unsigned int*   h1b = (unsigned int*)p;   p += (size_t)N * 64 * 2;
    unsigned int*   h2b = (unsigned int*)p;   p += (size_t)N * 256 * 2;

    hipMemsetAsync(d_ws, 0, zero_bytes, stream);

    int eb = (E + 255) / 256;

    // CSR build + casts
    k_hist   <<<eb, 256, 0, stream>>>(ei, deg, E);
    k_scan1  <<<nb, 256, 0, stream>>>(deg, rowptr, bsum, N);
    k_scan2  <<<1, 512, 0, stream>>>(bsum, nb);
    k_scan3  <<<nb, 256, 0, stream>>>(rowptr, cursor, bsum, N);
    {
        int M8 = N * 32 / 8;
        k_castx<<<(M8 + 255) / 256, 256, 0, stream>>>(x, (unsigned int*)xb, M8);
    }
    k_scatter<<<eb, 256, 0, stream>>>(ei, ea, cursor, csr2, eab, E);

    // conv1
    {
        int waves = (E + SPW1 - 1) / SPW1;
        int blocks = (waves + 3) / 4;
        k_agg1<<<blocks, 256, 0, stream>>>(xb, eab, We1, be1, csr2, agg1, E);
    }
    k_mlp1<<<nb64, 256, 0, stream>>>(x, agg1, W1a, b1a, W1b, b1b, h1,
                                     (unsigned int*)h1b, N);

    // conv2
    {
        int waves = (E + SPW2 - 1) / SPW2;
        int blocks = (waves + 3) / 4;
        k_agg2<<<blocks, 256, 0, stream>>>((unsigned short*)h1b, eab, We2, be2,
                                           csr2, agg2, E);
    }
    k_mlp2<<<nb64, 256, 0, stream>>>(h1, agg2, W2a, b2a, W2b, b2b,
                                     (unsigned int*)h2b, N);

    // pool + head
    k_pool<<<(N + 127) / 128, 256, 0, stream>>>((unsigned short*)h2b, batch,
                                                gbuf, N);
    k_head<<<G, 256, 0, stream>>>(gbuf, Wf0, bf0, Wf1, bf1, Wf2, bf2, Wr, br,
                                  (float*)d_out);
}

// Round 9
// 786.712 us; speedup vs baseline: 1.3302x; 1.3302x over previous
//
#include <hip/hip_runtime.h>

__device__ __forceinline__ float lrelu(float v){ return v > 0.f ? v : 0.01f*v; }

typedef __attribute__((ext_vector_type(8))) short v8s;   // 8 bf16 (4 VGPRs)
typedef __attribute__((ext_vector_type(4))) float v4f;   // MFMA acc

// bf16 helpers (RNE pack; unpack via shift)
__device__ __forceinline__ unsigned short f2bf(float f){
    union{float f; unsigned int i;} v; v.f = f;
    unsigned int u = v.i;
    return (unsigned short)((u + 0x7fffu + ((u >> 16) & 1u)) >> 16);
}
__device__ __forceinline__ unsigned int pack2(float a, float b){
    return (unsigned int)f2bf(a) | ((unsigned int)f2bf(b) << 16);
}
__device__ __forceinline__ float bflo(unsigned int u){
    union{unsigned int i; float f;} v; v.i = u << 16; return v.f;
}
__device__ __forceinline__ float bfhi(unsigned int u){
    union{unsigned int i; float f;} v; v.i = u & 0xffff0000u; return v.f;
}
__device__ __forceinline__ float bf2f(unsigned short s){
    union{unsigned int i; float f;} v; v.i = ((unsigned int)s) << 16; return v.f;
}

// ================= CSR build =================================================
__global__ __launch_bounds__(256) void k_hist(
    const int* __restrict__ ei, int* __restrict__ deg, int E)
{
    int e = blockIdx.x * 256 + threadIdx.x;
    if (e >= E) return;
    atomicAdd(&deg[ei[E + e]], 1);
}

__global__ __launch_bounds__(256) void k_scan1(
    const int* __restrict__ deg, int* __restrict__ rowptr,
    int* __restrict__ bsum, int N)
{
    __shared__ int sh[256];
    int t = threadIdx.x;
    int i = blockIdx.x * 256 + t;
    int v = (i < N) ? deg[i] : 0;
    sh[t] = v;
    __syncthreads();
    #pragma unroll
    for (int off = 1; off < 256; off <<= 1) {
        int add = (t >= off) ? sh[t - off] : 0;
        __syncthreads();
        sh[t] += add;
        __syncthreads();
    }
    if (i < N) rowptr[i] = sh[t] - v;
    if (t == 255) bsum[blockIdx.x] = sh[t];
}

__global__ __launch_bounds__(512) void k_scan2(int* __restrict__ bsum, int nb)
{
    __shared__ int sh[512];
    int t = threadIdx.x;
    int v = (t < nb) ? bsum[t] : 0;
    sh[t] = v;
    __syncthreads();
    #pragma unroll
    for (int off = 1; off < 512; off <<= 1) {
        int add = (t >= off) ? sh[t - off] : 0;
        __syncthreads();
        sh[t] += add;
        __syncthreads();
    }
    if (t < nb) bsum[t] = sh[t] - v;
}

__global__ __launch_bounds__(256) void k_scan3(
    int* __restrict__ rowptr, int* __restrict__ cursor,
    const int* __restrict__ bsum, int N)
{
    int i = blockIdx.x * 256 + threadIdx.x;
    if (i >= N) return;
    int rp = rowptr[i] + bsum[i >> 8];
    rowptr[i] = rp;
    cursor[i] = rp;
}

// cast x -> bf16 (8 floats / thread)
__global__ __launch_bounds__(256) void k_castx(
    const float* __restrict__ x, unsigned int* __restrict__ xb, int M8)
{
    int i = blockIdx.x * 256 + threadIdx.x;
    if (i >= M8) return;
    const float4* p = reinterpret_cast<const float4*>(x) + (size_t)i * 2;
    float4 a = p[0], b = p[1];
    uint4 o;
    o.x = pack2(a.x, a.y); o.y = pack2(a.z, a.w);
    o.z = pack2(b.x, b.y); o.w = pack2(b.z, b.w);
    reinterpret_cast<uint4*>(xb)[i] = o;
}

// one-time transpose+cast of conv2 nn weights to bf16 [N][K] layout
__global__ __launch_bounds__(256) void k_castw(
    const float* __restrict__ W2a, const float* __restrict__ W2b,
    unsigned short* __restrict__ W2aT, unsigned short* __restrict__ W2bT)
{
    int i = blockIdx.x * 256 + threadIdx.x;
    if (i < 128 * 64) {
        int n = i >> 6, k = i & 63;
        W2aT[i] = f2bf(W2a[k * 128 + n]);
    }
    int j = i - 128 * 64;
    if (j >= 0 && j < 256 * 128) {
        int n = j >> 7, k = j & 127;
        W2bT[j] = f2bf(W2b[k * 256 + n]);
    }
}

// scatter: csr2[slot]={src,dst}; eab[slot]=16 bf16 of ea row (CSR order)
__global__ __launch_bounds__(256) void k_scatter(
    const int* __restrict__ ei, const float* __restrict__ ea,
    int* __restrict__ cursor, int2* __restrict__ csr2,
    uint4* __restrict__ eab, int E)
{
    int e = blockIdx.x * 256 + threadIdx.x;
    if (e >= E) return;
    int s = ei[e];
    int d = ei[E + e];
    int slot = atomicAdd(&cursor[d], 1);
    const float4* p = reinterpret_cast<const float4*>(ea) + (size_t)e * 4;
    float4 a = p[0], b = p[1], c = p[2], f = p[3];
    uint4 o0, o1;
    o0.x = pack2(a.x, a.y); o0.y = pack2(a.z, a.w);
    o0.z = pack2(b.x, b.y); o0.w = pack2(b.z, b.w);
    o1.x = pack2(c.x, c.y); o1.y = pack2(c.z, c.w);
    o1.z = pack2(f.x, f.y); o1.w = pack2(f.z, f.w);
    eab[(size_t)slot * 2]     = o0;
    eab[(size_t)slot * 2 + 1] = o1;
    int2 r; r.x = s; r.y = d;
    csr2[slot] = r;
}

// ============ conv1 aggregation: edge-major bf16, SW-pipelined ===============
#define SPW1 128
__global__ __launch_bounds__(256) void k_agg1(
    const unsigned short* __restrict__ xb, const uint4* __restrict__ eab,
    const float* __restrict__ We, const float* __restrict__ be,
    const int2* __restrict__ csr2, float* __restrict__ agg, int E)
{
    const int tid = threadIdx.x;
    const int c = tid & 31;
    const int half = (tid >> 5) & 1;
    const int wave = __builtin_amdgcn_readfirstlane((blockIdx.x * 256 + tid) >> 6);
    const long s0 = (long)wave * SPW1;
    if (s0 >= E) return;
    const long send = (s0 + SPW1 < (long)E) ? s0 + SPW1 : (long)E;

    float w[16];
    #pragma unroll
    for (int k = 0; k < 16; ++k) w[k] = We[k * 32 + c];
    const float bias = be[c];

    long sl = s0 + half;
    if (sl >= send) return;

    int2 rec = csr2[sl];
    float xv = bf2f(xb[(size_t)rec.x * 32 + c]);
    uint4 a0 = eab[sl * 2], a1 = eab[sl * 2 + 1];
    int cur = rec.y;
    float acc = 0.f;
    bool more = true;
    do {
        long nxt = sl + 2;
        more = (nxt < send);
        int2 recn; float xvn; uint4 b0, b1;
        if (more) {
            recn = csr2[nxt];
            xvn = bf2f(xb[(size_t)recn.x * 32 + c]);
            b0 = eab[nxt * 2]; b1 = eab[nxt * 2 + 1];
        }
        if (rec.y != cur) {
            atomicAdd(&agg[(size_t)cur * 32 + c], acc);
            acc = 0.f; cur = rec.y;
        }
        float m = bias;
        m = fmaf(bflo(a0.x), w[0],  m); m = fmaf(bfhi(a0.x), w[1],  m);
        m = fmaf(bflo(a0.y), w[2],  m); m = fmaf(bfhi(a0.y), w[3],  m);
        m = fmaf(bflo(a0.z), w[4],  m); m = fmaf(bfhi(a0.z), w[5],  m);
        m = fmaf(bflo(a0.w), w[6],  m); m = fmaf(bfhi(a0.w), w[7],  m);
        m = fmaf(bflo(a1.x), w[8],  m); m = fmaf(bfhi(a1.x), w[9],  m);
        m = fmaf(bflo(a1.y), w[10], m); m = fmaf(bfhi(a1.y), w[11], m);
        m = fmaf(bflo(a1.z), w[12], m); m = fmaf(bfhi(a1.z), w[13], m);
        m = fmaf(bflo(a1.w), w[14], m); m = fmaf(bfhi(a1.w), w[15], m);
        m += xv;
        acc += (m > 0.f ? m : 0.f);
        if (more) { rec = recn; xv = xvn; a0 = b0; a1 = b1; }
        sl = nxt;
    } while (more);
    atomicAdd(&agg[(size_t)cur * 32 + c], acc);
}

// ============ conv2 aggregation: edge-major bf16, wave-uniform ===============
#define SPW2 64
__global__ __launch_bounds__(256) void k_agg2(
    const unsigned short* __restrict__ h1b, const uint4* __restrict__ eab,
    const float* __restrict__ We, const float* __restrict__ be,
    const int2* __restrict__ csr2, float* __restrict__ agg, int E)
{
    const int tid = threadIdx.x;
    const int c = tid & 63;
    const int wave = __builtin_amdgcn_readfirstlane((blockIdx.x * 256 + tid) >> 6);
    const long s0 = (long)wave * SPW2;
    if (s0 >= E) return;
    const long send = (s0 + SPW2 < (long)E) ? s0 + SPW2 : (long)E;

    float w[16];
    #pragma unroll
    for (int k = 0; k < 16; ++k) w[k] = We[k * 64 + c];
    const float bias = be[c];

    long sl = s0;
    int2 rec = csr2[sl];
    float hv = bf2f(h1b[(size_t)rec.x * 64 + c]);
    uint4 a0 = eab[sl * 2], a1 = eab[sl * 2 + 1];
    int cur = rec.y;
    bool owned = false;
    float acc = 0.f;
    bool more = true;
    do {
        long nxt = sl + 1;
        more = (nxt < send);
        int2 recn; float hvn; uint4 b0, b1;
        if (more) {
            recn = csr2[nxt];
            hvn = bf2f(h1b[(size_t)recn.x * 64 + c]);
            b0 = eab[nxt * 2]; b1 = eab[nxt * 2 + 1];
        }
        if (rec.y != cur) {
            if (owned) agg[(size_t)cur * 64 + c] = acc;
            else       atomicAdd(&agg[(size_t)cur * 64 + c], acc);
            acc = 0.f; cur = rec.y; owned = true;
        }
        float m = bias;
        m = fmaf(bflo(a0.x), w[0],  m); m = fmaf(bfhi(a0.x), w[1],  m);
        m = fmaf(bflo(a0.y), w[2],  m); m = fmaf(bfhi(a0.y), w[3],  m);
        m = fmaf(bflo(a0.z), w[4],  m); m = fmaf(bfhi(a0.z), w[5],  m);
        m = fmaf(bflo(a0.w), w[6],  m); m = fmaf(bfhi(a0.w), w[7],  m);
        m = fmaf(bflo(a1.x), w[8],  m); m = fmaf(bfhi(a1.x), w[9],  m);
        m = fmaf(bflo(a1.y), w[10], m); m = fmaf(bfhi(a1.y), w[11], m);
        m = fmaf(bflo(a1.z), w[12], m); m = fmaf(bfhi(a1.z), w[13], m);
        m = fmaf(bflo(a1.w), w[14], m); m = fmaf(bfhi(a1.w), w[15], m);
        m += hv;
        acc += (m > 0.f ? m : 0.f);
        if (more) { rec = recn; hv = hvn; a0 = b0; a1 = b1; }
        sl = nxt;
    } while (more);
    atomicAdd(&agg[(size_t)cur * 64 + c], acc);
}

// ============ conv1 node nn, fused; writes h1 fp32 + h1b bf16 ================
__global__ __launch_bounds__(256, 4) void k_mlp1(
    const float* __restrict__ x, const float* __restrict__ agg1,
    const float* __restrict__ W1a, const float* __restrict__ b1a,
    const float* __restrict__ W1b, const float* __restrict__ b1b,
    float* __restrict__ h1, unsigned int* __restrict__ h1b, int N)
{
    __shared__ float ts[64][33];
    const int tid = threadIdx.x;
    const int n0 = blockIdx.x * 64;
    const int row = tid & 63;
    const int grp = __builtin_amdgcn_readfirstlane(tid >> 6);
    const int g = n0 + row;

    float hv[32];
    if (g < N) {
        const float4* xp = reinterpret_cast<const float4*>(x) + (size_t)g * 8;
        const float4* ap = reinterpret_cast<const float4*>(agg1) + (size_t)g * 8;
        #pragma unroll
        for (int q = 0; q < 8; ++q) {
            float4 a = xp[q], b = ap[q];
            hv[4*q+0]=a.x+b.x; hv[4*q+1]=a.y+b.y;
            hv[4*q+2]=a.z+b.z; hv[4*q+3]=a.w+b.w;
        }
    } else {
        #pragma unroll
        for (int q = 0; q < 32; ++q) hv[q] = 0.f;
    }

    {
        const int c0 = grp * 8;
        float acc[8];
        #pragma unroll
        for (int i = 0; i < 8; ++i) acc[i] = b1a[c0 + i];
        for (int k = 0; k < 32; ++k) {
            float h = hv[k];
            const float* w = W1a + k*32 + c0;
            #pragma unroll
            for (int i = 0; i < 8; ++i) acc[i] = fmaf(h, w[i], acc[i]);
        }
        #pragma unroll
        for (int i = 0; i < 8; ++i) ts[row][c0 + i] = lrelu(acc[i]);
    }
    __syncthreads();

    {
        const int c0 = grp * 16;
        float acc[16];
        #pragma unroll
        for (int i = 0; i < 16; ++i) acc[i] = b1b[c0 + i];
        for (int k = 0; k < 32; ++k) {
            float tv = ts[row][k];
            const float* w = W1b + k*64 + c0;
            #pragma unroll
            for (int i = 0; i < 16; ++i) acc[i] = fmaf(tv, w[i], acc[i]);
        }
        if (g < N) {
            #pragma unroll
            for (int i = 0; i < 16; ++i) acc[i] = lrelu(acc[i]);
            float4* op = reinterpret_cast<float4*>(h1) + (size_t)g*16 + (c0>>2);
            #pragma unroll
            for (int q = 0; q < 4; ++q) {
                float4 o;
                o.x = acc[4*q+0]; o.y = acc[4*q+1];
                o.z = acc[4*q+2]; o.w = acc[4*q+3];
                op[q] = o;
            }
            uint4 p0, p1;
            p0.x = pack2(acc[0],  acc[1]);  p0.y = pack2(acc[2],  acc[3]);
            p0.z = pack2(acc[4],  acc[5]);  p0.w = pack2(acc[6],  acc[7]);
            p1.x = pack2(acc[8],  acc[9]);  p1.y = pack2(acc[10], acc[11]);
            p1.z = pack2(acc[12], acc[13]); p1.w = pack2(acc[14], acc[15]);
            uint4* bp = reinterpret_cast<uint4*>(h1b + (size_t)g*32 + (c0>>1));
            bp[0] = p0; bp[1] = p1;
        }
    }
}

// ============ conv2 node nn via MFMA bf16 ====================================
// 64 nodes/block; wave wv owns m-tile rows [wv*16, wv*16+16).
// Layouts (verified, guide §3): A[m=lane&15][k=quad*8+j]; C/D col=lane&15,
// row=quad*4+reg. Weights pre-transposed bf16 [N][K] so B-frag = contiguous k.
__global__ __launch_bounds__(256) void k_mlp2(
    const float* __restrict__ h1, const float* __restrict__ agg2,
    const unsigned short* __restrict__ W2aT, const float* __restrict__ b2a,
    const unsigned short* __restrict__ W2bT, const float* __restrict__ b2b,
    unsigned short* __restrict__ h2b, int N)
{
    __shared__ unsigned short hs[64][72];    // 64 x 64 bf16 (+pad)
    __shared__ unsigned short ts[64][136];   // 64 x 128 bf16 (+pad)
    const int tid = threadIdx.x;
    const int n0 = blockIdx.x * 64;

    // stage hs = bf16(h1 + agg2)
    {
        int r = tid >> 2, cseg = (tid & 3) * 16;
        int g = n0 + r;
        uint4 o0 = {0,0,0,0}, o1 = {0,0,0,0};
        if (g < N) {
            const float4* xp = reinterpret_cast<const float4*>(h1)
                               + (size_t)g*16 + (cseg>>2);
            const float4* ap = reinterpret_cast<const float4*>(agg2)
                               + (size_t)g*16 + (cseg>>2);
            float4 a0=xp[0], a1=xp[1], a2=xp[2], a3=xp[3];
            float4 b0=ap[0], b1=ap[1], b2=ap[2], b3=ap[3];
            o0.x = pack2(a0.x+b0.x, a0.y+b0.y); o0.y = pack2(a0.z+b0.z, a0.w+b0.w);
            o0.z = pack2(a1.x+b1.x, a1.y+b1.y); o0.w = pack2(a1.z+b1.z, a1.w+b1.w);
            o1.x = pack2(a2.x+b2.x, a2.y+b2.y); o1.y = pack2(a2.z+b2.z, a2.w+b2.w);
            o1.z = pack2(a3.x+b3.x, a3.y+b3.y); o1.w = pack2(a3.z+b3.z, a3.w+b3.w);
        }
        uint4* dp = reinterpret_cast<uint4*>(&hs[r][cseg]);
        dp[0] = o0; dp[1] = o1;
    }
    __syncthreads();

    const int wv   = __builtin_amdgcn_readfirstlane(tid >> 6);
    const int lane = tid & 63;
    const int lid  = lane & 15;
    const int quad = lane >> 4;

    // layer A: [16x64] @ [64x128] -> ts
    v8s afA0 = *reinterpret_cast<const v8s*>(&hs[wv*16 + lid][quad*8]);
    v8s afA1 = *reinterpret_cast<const v8s*>(&hs[wv*16 + lid][32 + quad*8]);
    #pragma unroll
    for (int nt = 0; nt < 8; ++nt) {
        v4f acc = {0.f, 0.f, 0.f, 0.f};
        const unsigned short* wp = W2aT + (nt*16 + lid)*64 + quad*8;
        v8s b0 = *reinterpret_cast<const v8s*>(wp);
        v8s b1 = *reinterpret_cast<const v8s*>(wp + 32);
        acc = __builtin_amdgcn_mfma_f32_16x16x32_bf16(afA0, b0, acc, 0, 0, 0);
        acc = __builtin_amdgcn_mfma_f32_16x16x32_bf16(afA1, b1, acc, 0, 0, 0);
        float bias = b2a[nt*16 + lid];
        #pragma unroll
        for (int i = 0; i < 4; ++i) {
            float v = lrelu(acc[i] + bias);
            ts[wv*16 + quad*4 + i][nt*16 + lid] = f2bf(v);
        }
    }
    __syncthreads();

    // layer B: [16x128] @ [128x256] -> h2b (bf16)
    v8s afB[4];
    #pragma unroll
    for (int ks = 0; ks < 4; ++ks)
        afB[ks] = *reinterpret_cast<const v8s*>(&ts[wv*16 + lid][ks*32 + quad*8]);
    const int gbase = n0 + wv*16 + quad*4;
    #pragma unroll 4
    for (int nt = 0; nt < 16; ++nt) {
        v4f acc = {0.f, 0.f, 0.f, 0.f};
        const unsigned short* wp = W2bT + (nt*16 + lid)*128 + quad*8;
        #pragma unroll
        for (int ks = 0; ks < 4; ++ks) {
            v8s bf = *reinterpret_cast<const v8s*>(wp + ks*32);
            acc = __builtin_amdgcn_mfma_f32_16x16x32_bf16(afB[ks], bf, acc, 0, 0, 0);
        }
        float bias = b2b[nt*16 + lid];
        #pragma unroll
        for (int i = 0; i < 4; ++i) {
            int g = gbase + i;
            if (g < N) {
                float v = lrelu(acc[i] + bias);
                h2b[(size_t)g*256 + nt*16 + lid] = f2bf(v);
            }
        }
    }
}

// ---------------- global_add_pool over sorted batch ids (bf16 h2) -------------
__global__ __launch_bounds__(256) void k_pool(
    const unsigned short* __restrict__ h2b, const int* __restrict__ batch,
    float* __restrict__ g, int N)
{
    int c = threadIdx.x;
    int n0 = blockIdx.x * 128;
    int nend = n0 + 128; if (nend > N) nend = N;
    float acc = 0.f;
    int cur = batch[n0];
    for (int n = n0; n < nend; ++n) {
        int b = batch[n];
        if (b != cur) {
            atomicAdd(&g[(size_t)cur*256 + c], acc);
            acc = 0.f; cur = b;
        }
        acc += bf2f(h2b[(size_t)n*256 + c]);
    }
    atomicAdd(&g[(size_t)cur*256 + c], acc);
}

// ---------------- head MLP -----------------------------------------------------
__global__ __launch_bounds__(256) void k_head(
    const float* __restrict__ g,
    const float* __restrict__ Wf0, const float* __restrict__ bf0,
    const float* __restrict__ Wf1, const float* __restrict__ bf1,
    const float* __restrict__ Wf2, const float* __restrict__ bf2,
    const float* __restrict__ Wr,  const float* __restrict__ br,
    float* __restrict__ out)
{
    __shared__ float buf[256];
    __shared__ float t0[128];
    __shared__ float t1[64];
    __shared__ float t2[32];
    int gid = blockIdx.x, tid = threadIdx.x;
    buf[tid] = g[(size_t)gid*256 + tid];
    __syncthreads();
    if (tid < 128) {
        float acc = bf0[tid];
        for (int k = 0; k < 256; ++k) acc = fmaf(buf[k], Wf0[k*128 + tid], acc);
        t0[tid] = lrelu(acc);
    }
    __syncthreads();
    if (tid < 64) {
        float acc = bf1[tid];
        for (int k = 0; k < 128; ++k) acc = fmaf(t0[k], Wf1[k*64 + tid], acc);
        t1[tid] = lrelu(acc);
    }
    __syncthreads();
    if (tid < 32) {
        float acc = bf2[tid];
        for (int k = 0; k < 64; ++k) acc = fmaf(t1[k], Wf2[k*32 + tid], acc);
        t2[tid] = lrelu(acc);
    }
    __syncthreads();
    if (tid == 0) {
        float acc = br[0];
        for (int k = 0; k < 32; ++k) acc = fmaf(t2[k], Wr[k], acc);
        out[gid] = acc;
    }
}

extern "C" void kernel_launch(void* const* d_in, const int* in_sizes, int n_in,
                              void* d_out, int out_size, void* d_ws, size_t ws_size,
                              hipStream_t stream)
{
    const float* x     = (const float*)d_in[0];
    const int*   ei    = (const int*)d_in[1];
    const float* ea    = (const float*)d_in[2];
    const int*   batch = (const int*)d_in[3];
    const float* We1=(const float*)d_in[4],  *be1=(const float*)d_in[5];
    const float* W1a=(const float*)d_in[6],  *b1a=(const float*)d_in[7];
    const float* W1b=(const float*)d_in[8],  *b1b=(const float*)d_in[9];
    const float* We2=(const float*)d_in[10], *be2=(const float*)d_in[11];
    const float* W2a=(const float*)d_in[12], *b2a=(const float*)d_in[13];
    const float* W2b=(const float*)d_in[14], *b2b=(const float*)d_in[15];
    const float* Wf0=(const float*)d_in[16], *bf0=(const float*)d_in[17];
    const float* Wf1=(const float*)d_in[18], *bf1=(const float*)d_in[19];
    const float* Wf2=(const float*)d_in[20], *bf2=(const float*)d_in[21];
    const float* Wr =(const float*)d_in[22], *br =(const float*)d_in[23];

    const int N = in_sizes[0] / 32;
    const int E = in_sizes[1] / 2;
    const int G = out_size;
    const int nb = (N + 255) / 256;
    const int nb64 = (N + 63) / 64;

    // ---- workspace layout ----
    // zeroed prefix: [deg N][gbuf G*256 f32][agg1 N*32 f32][agg2 N*64 f32]
    char* p = (char*)d_ws;
    int*   deg     = (int*)p;                 p += (size_t)N * 4;
    float* gbuf    = (float*)p;               p += (size_t)G * 256 * 4;
    float* agg1    = (float*)p;               p += (size_t)N * 32 * 4;
    float* agg2    = (float*)p;               p += (size_t)N * 64 * 4;
    size_t zero_bytes = (size_t)(p - (char*)d_ws);
    int*   rowptr  = (int*)p;                 p += (size_t)N * 4;
    int*   cursor  = (int*)p;                 p += (size_t)N * 4;
    int*   bsum    = (int*)p;                 p += 512 * 4;
    p = (char*)(((uintptr_t)p + 15) & ~(uintptr_t)15);
    int2*  csr2    = (int2*)p;                p += (size_t)E * 8;
    uint4* eab     = (uint4*)p;               p += (size_t)E * 32;   // 16 bf16/edge
    unsigned short* xb   = (unsigned short*)p; p += (size_t)N * 32 * 2;
    float* h1      = (float*)p;               p += (size_t)N * 64 * 4;
    unsigned int*   h1b  = (unsigned int*)p;  p += (size_t)N * 64 * 2;
    unsigned short* W2aT = (unsigned short*)p; p += 128 * 64 * 2;
    unsigned short* W2bT = (unsigned short*)p; p += 256 * 128 * 2;
    unsigned short* h2b  = (unsigned short*)p; p += (size_t)N * 256 * 2;

    hipMemsetAsync(d_ws, 0, zero_bytes, stream);

    int eb = (E + 255) / 256;

    // CSR build + casts
    k_hist   <<<eb, 256, 0, stream>>>(ei, deg, E);
    k_scan1  <<<nb, 256, 0, stream>>>(deg, rowptr, bsum, N);
    k_scan2  <<<1, 512, 0, stream>>>(bsum, nb);
    k_scan3  <<<nb, 256, 0, stream>>>(rowptr, cursor, bsum, N);
    {
        int M8 = N * 32 / 8;
        k_castx<<<(M8 + 255) / 256, 256, 0, stream>>>(x, (unsigned int*)xb, M8);
    }
    k_castw<<<(128*64 + 256*128 + 255) / 256, 256, 0, stream>>>(W2a, W2b, W2aT, W2bT);
    k_scatter<<<eb, 256, 0, stream>>>(ei, ea, cursor, csr2, eab, E);

    // conv1
    {
        int waves = (E + SPW1 - 1) / SPW1;
        int blocks = (waves + 3) / 4;
        k_agg1<<<blocks, 256, 0, stream>>>(xb, eab, We1, be1, csr2, agg1, E);
    }
    k_mlp1<<<nb64, 256, 0, stream>>>(x, agg1, W1a, b1a, W1b, b1b, h1,
                                     (unsigned int*)h1b, N);

    // conv2
    {
        int waves = (E + SPW2 - 1) / SPW2;
        int blocks = (waves + 3) / 4;
        k_agg2<<<blocks, 256, 0, stream>>>((unsigned short*)h1b, eab, We2, be2,
                                           csr2, agg2, E);
    }
    k_mlp2<<<nb64, 256, 0, stream>>>(h1, agg2, W2aT, b2a, W2bT, b2b, h2b, N);

    // pool + head
    k_pool<<<(N + 127) / 128, 256, 0, stream>>>(h2b, batch, gbuf, N);
    k_head<<<G, 256, 0, stream>>>(gbuf, Wf0, bf0, Wf1, bf1, Wf2, bf2, Wr, br,
                                  (float*)d_out);
}